// Round 9
// baseline (631.760 us; speedup 1.0000x reference)
//
#include <hip/hip_runtime.h>

typedef unsigned short us;
typedef us us4 __attribute__((ext_vector_type(4)));
typedef us us8 __attribute__((ext_vector_type(8)));
typedef short bf16x8 __attribute__((ext_vector_type(8)));
typedef float f32x4 __attribute__((ext_vector_type(4)));

#define DEVI static __device__ __forceinline__

// constants for this problem instance
#define BB 16
#define NN 4096
#define PP 256
#define CC 8
#define MM (BB * NN)   // 65536

DEVI float bf2f(us u) { unsigned x = ((unsigned)u) << 16; return __builtin_bit_cast(float, x); }
DEVI us f2bf(float f) {
  unsigned x = __builtin_bit_cast(unsigned, f);
  x += 0x7fffu + ((x >> 16) & 1u);   // round to nearest even
  return (us)(x >> 16);
}

DEVI void gload_lds16(const void* g, void* l) {
  __builtin_amdgcn_global_load_lds(
      (const __attribute__((address_space(1))) void*)g,
      (__attribute__((address_space(3))) void*)l, 16, 0, 0);
}

DEVI float sigf(float x) { return 1.f / (1.f + __expf(-x)); }
DEVI float tanhfast(float a) {
  float aa = fabsf(a);
  float t = 1.f - 2.f / (1.f + __expf(2.f * aa));
  return copysignf(t, a);
}

// ---------------- weight prep: fp32 -> bf16, concatenated / gate-interleaved ----
// Wg layout (shuffle-free): row R -> J16 = R>>6, gate g = (R>>4)&3, c = R&15,
// output col j = J16*16 + c. Over K=512 ([h | s]):
//   g=0 (r):  [W_ih_r | W_hh_r]   g=1 (z): [W_ih_z | W_hh_z]
//   g=2 (xn): [W_ih_n | 0]        g=3 (hn): [0 | W_hh_n]
__global__ void k_prep(const float* __restrict__ Wres,
                       const float* __restrict__ Wpar, const float* __restrict__ bpar,
                       const float* __restrict__ Wnbr, const float* __restrict__ bnbr,
                       const float* __restrict__ Wih, const float* __restrict__ Whh,
                       const float* __restrict__ bih, const float* __restrict__ bhh,
                       us* __restrict__ Wr, us* __restrict__ Wcat, float* __restrict__ bcat,
                       us* __restrict__ Wg, float* __restrict__ bg) {
  int tid = blockIdx.x * blockDim.x + threadIdx.x;
  int nth = gridDim.x * blockDim.x;
  for (int i = tid; i < 256 * 256; i += nth) Wr[i] = f2bf(Wres[i]);
  for (int i = tid; i < 256 * 512; i += nth) {
    int o = i >> 9, k = i & 511;
    float v = (k < 256) ? Wpar[o * 256 + k] : Wnbr[o * 256 + (k - 256)];
    Wcat[i] = f2bf(v);
  }
  for (int i = tid; i < 256; i += nth) bcat[i] = bpar[i] + bnbr[i];
  for (int i = tid; i < 1024 * 512; i += nth) {
    int R = i >> 9, k = i & 511;
    int g = (R >> 4) & 3, j = ((R >> 6) << 4) + (R & 15);
    float v = 0.f;
    if (g == 0)      v = (k < 256) ? Wih[j * 256 + k]         : Whh[j * 256 + (k - 256)];
    else if (g == 1) v = (k < 256) ? Wih[(256 + j) * 256 + k] : Whh[(256 + j) * 256 + (k - 256)];
    else if (g == 2) v = (k < 256) ? Wih[(512 + j) * 256 + k] : 0.f;
    else             v = (k < 256) ? 0.f                      : Whh[(512 + j) * 256 + (k - 256)];
    Wg[i] = f2bf(v);
  }
  for (int i = tid; i < 1024; i += nth) {
    int g = (i >> 4) & 3, j = ((i >> 6) << 4) + (i & 15);
    float v;
    if (g == 0)      v = bih[j] + bhh[j];
    else if (g == 1) v = bih[256 + j] + bhh[256 + j];
    else if (g == 2) v = bih[512 + j];
    else             v = bhh[512 + j];
    bg[i] = v;
  }
}

// ---------------- x fp32 -> bf16 (vectorized) ----------------
__global__ __launch_bounds__(256) void k_f2bf(const float* __restrict__ x,
                                              us* __restrict__ o, int n8) {
  int i = blockIdx.x * blockDim.x + threadIdx.x;
  if (i >= n8) return;
  const float4* p = (const float4*)x + (size_t)i * 2;
  float4 a = p[0], b = p[1];
  us8 r;
  r[0] = f2bf(a.x); r[1] = f2bf(a.y); r[2] = f2bf(a.z); r[3] = f2bf(a.w);
  r[4] = f2bf(b.x); r[5] = f2bf(b.y); r[6] = f2bf(b.z); r[7] = f2bf(b.w);
  *(us8*)(o + (size_t)i * 8) = r;
}

// ---------------- gather: A_cat = [h[parent] | avg children h] (bf16) ----------
__global__ __launch_bounds__(256)
void k_gather(const us* __restrict__ h, const int* __restrict__ par,
              const int* __restrict__ chd, const int* __restrict__ cnt,
              us* __restrict__ Acat) {
  int wid = (blockIdx.x * blockDim.x + threadIdx.x) >> 6;  // one wave per node
  int l = threadIdx.x & 63;
  int m = wid;                       // 0..MM-1
  int b = m >> 12;                   // N = 4096
  int rowP = (b << 12) + par[m];
  us4 pv = *((const us4*)(h + ((size_t)rowP << 8)) + l);
  *((us4*)(Acat + ((size_t)m << 9)) + l) = pv;
  int c = cnt[m];
  float inv = 1.f / (float)c;
  const int* ch = chd + (size_t)m * CC;
  us4 cv[CC];
#pragma unroll
  for (int i = 0; i < CC; ++i) {
    int rowC = (b << 12) + ch[i];
    cv[i] = *((const us4*)(h + ((size_t)rowC << 8)) + l);
  }
  float a0 = 0.f, a1 = 0.f, a2 = 0.f, a3 = 0.f;
#pragma unroll
  for (int i = 0; i < CC; ++i) {
    float wgt = (i < c) ? 1.f : 0.f;
    a0 += wgt * bf2f(cv[i][0]); a1 += wgt * bf2f(cv[i][1]);
    a2 += wgt * bf2f(cv[i][2]); a3 += wgt * bf2f(cv[i][3]);
  }
  us4 nb;
  nb[0] = f2bf(a0 * inv); nb[1] = f2bf(a1 * inv);
  nb[2] = f2bf(a2 * inv); nb[3] = f2bf(a3 * inv);
  *((us4*)(Acat + ((size_t)m << 9) + 256) + l) = nb;
}

// ---------------- B fragments: global(L2-hot) -> VGPR, MFMA layout -------------
template <int M4, int KTOTc>
DEVI void loadB(const us* __restrict__ Bw, int nBase, int wc, int l, int kt,
                bf16x8 (&b)[2][4]) {
#pragma unroll
  for (int ks = 0; ks < 2; ++ks)
#pragma unroll
    for (int j = 0; j < 4; ++j)
      if (M4 & (1 << j)) {
        int row = nBase + wc * 64 + j * 16 + (l & 15);
        b[ks][j] = *(const bf16x8*)(Bw + (size_t)row * KTOTc + kt + ks * 32 + ((l >> 4) * 8));
      }
}

// ---------------- MFMA K-tile: A from LDS (64 rows, swizzled), B from regs -----
template <int M4>
DEVI void mma_tile(const us* As, int l, const bf16x8 (&b)[2][4], f32x4 (&acc)[4][4]) {
#pragma unroll
  for (int ks = 0; ks < 2; ++ks) {
    bf16x8 af[4];
#pragma unroll
    for (int i = 0; i < 4; ++i) {
      int row = i * 16 + (l & 15);
      int kb = ((ks * 32 + (l >> 4) * 8) * 2) ^ ((row & 7) << 4);  // swizzled read
      af[i] = *(const bf16x8*)((const char*)As + row * 128 + kb);
    }
#pragma unroll
    for (int i = 0; i < 4; ++i)
#pragma unroll
      for (int j = 0; j < 4; ++j)
        if (M4 & (1 << j))
          acc[i][j] = __builtin_amdgcn_mfma_f32_16x16x32_bf16(af[i], b[ks][j], acc[i][j], 0, 0, 0);
  }
}

DEVI void raw_barrier() {
  __builtin_amdgcn_sched_barrier(0);
  __builtin_amdgcn_s_barrier();      // RAW barrier: no implicit vmcnt(0) drain
  __builtin_amdgcn_sched_barrier(0);
}

// ---------------- GEMM: C = A @ Bw^T (+bias), 64x256 tile, 4 waves -------------
// R9 STRUCTURE: m97 occupancy regime. acc[4][4]=64 regs/wave -> total VGPR
// ~130-150 -> 3 waves/SIMD, ~3 blocks/CU co-resident (LDS only 16 KB dbuf).
// Cross-block wave overlap (m114) absorbs barrier/drain/B-load latency that
// capped R5-R8 at 2 waves/SIMD (232-reg acc[8][4] variants, all ~103-115 µs).
// B operand: global(L2-hot)->VGPR fragments, compiler-scheduled.
// Per K-tile: stageA(t+1) [2 gload_lds] -> loadB(t) [6-8 loads] ->
//   s_waitcnt vmcnt(stage+B outstanding) (A(t) landed) -> raw barrier ->
//   mma_tile -> raw barrier.
// NOTE (R2 lesson): never CAP regs below need — launch_bounds stays (256,2)
// (cap 256); occupancy comes from the naturally small allocation, not a cap.
template <int EPI, int KTOT, int KSPLIT, int NT>
__global__ __launch_bounds__(256, 2)
void k_gemm(const us* __restrict__ A0, const us* __restrict__ A1, int strideA,
            const us* __restrict__ Bw, const float* __restrict__ bias,
            us* __restrict__ outBf, float* __restrict__ outF,
            const float* __restrict__ sF, int writeF32) {
  __shared__ __align__(16) us sA[2][64 * 64];
  int tid = threadIdx.x;
  int w = tid >> 6, l = tid & 63;
  int wc = w;                        // 4 waves across N; each owns 64x64
  int bid = blockIdx.x;
  int per = gridDim.x >> 3;
  int g = (bid & 7) * per + (bid >> 3);
  int mi, ni;
  if (NT == 1) { mi = g; ni = 0; }
  else         { mi = g / NT; ni = g - mi * NT; }
  int mBase = mi * 64, nBase = ni * 256;
  f32x4 acc[4][4] = {};
  bf16x8 bfr[2][4];

  auto stageA = [&](int t) {
    int kt = t * 64, buf = t & 1;
    const us* aSrc; int kOff;
    if (kt < KSPLIT) { aSrc = A0; kOff = kt; }
    else             { aSrc = A1; kOff = kt - KSPLIT; }
#pragma unroll
    for (int p = 0; p < 2; ++p) {
      int row = p * 32 + (tid >> 3);
      int kb = ((tid & 7) * 16) ^ ((row & 7) << 4);   // pre-swizzled global source
      const char* ga = (const char*)(aSrc + (size_t)(mBase + row) * strideA + kOff) + kb;
      gload_lds16(ga, (char*)sA[buf] + row * 128 + (tid & 7) * 16);
    }
  };

  constexpr int NKT = KTOT / 64;
  stageA(0);
#pragma unroll
  for (int t = 0; t < NKT; ++t) {
    bool more = (t + 1 < NKT);
    if (more) stageA(t + 1);
    if (EPI == 2) {
      if (t * 64 < KSPLIT) loadB<0b0111, KTOT>(Bw, nBase, wc, l, t * 64, bfr);
      else                 loadB<0b1011, KTOT>(Bw, nBase, wc, l, t * 64, bfr);
    } else {
      loadB<0b1111, KTOT>(Bw, nBase, wc, l, t * 64, bfr);
    }
    // wait until only {A(t+1) stage (2) + B(t) (6/8)} outstanding => A(t) landed
    if (more) {
      if (EPI == 2) asm volatile("s_waitcnt vmcnt(8)" ::: "memory");
      else          asm volatile("s_waitcnt vmcnt(10)" ::: "memory");
    } else {
      if (EPI == 2) asm volatile("s_waitcnt vmcnt(6)" ::: "memory");
      else          asm volatile("s_waitcnt vmcnt(8)" ::: "memory");
    }
    raw_barrier();                     // all waves' A(t) LDS writes visible
    const us* Acur = sA[t & 1];
    if (EPI == 2) {
      if (t * 64 < KSPLIT) mma_tile<0b0111>(Acur, l, bfr, acc);  // skip hn (j=3)
      else                 mma_tile<0b1011>(Acur, l, bfr, acc);  // skip xn (j=2)
    } else {
      mma_tile<0b1111>(Acur, l, bfr, acc);
    }
    raw_barrier();                     // reads of buf done before restage
  }

  int rBase0 = mBase;                  // wave spans all 64 M rows
  int cBase0 = nBase + wc * 64;
  if (EPI == 0 || EPI == 1) {
#pragma unroll
    for (int i = 0; i < 4; ++i)
#pragma unroll
      for (int j = 0; j < 4; ++j) {
        int col = cBase0 + j * 16 + (l & 15);
        int row0 = rBase0 + i * 16 + ((l >> 4) << 2);
        float bb = bias[col];
#pragma unroll
        for (int e = 0; e < 4; ++e) {
          float v = acc[i][j][e] + bb;
          size_t off = (size_t)(row0 + e) * 256 + col;
          outBf[off] = f2bf(v);
          if (EPI == 1) outF[off] = v;
        }
      }
  } else {
    // shuffle-free: j-fragment == gate (wave spans 64 gate-cols = 16 out cols)
    int outCol = ((nBase >> 6) + wc) * 16 + (l & 15);
    float b0 = bias[cBase0 + 0  + (l & 15)];
    float b1 = bias[cBase0 + 16 + (l & 15)];
    float b2 = bias[cBase0 + 32 + (l & 15)];
    float b3 = bias[cBase0 + 48 + (l & 15)];
#pragma unroll
    for (int i = 0; i < 4; ++i) {
      int row0 = rBase0 + i * 16 + ((l >> 4) << 2);
#pragma unroll
      for (int e = 0; e < 4; ++e) {
        float r = sigf(acc[i][0][e] + b0);
        float z = sigf(acc[i][1][e] + b1);
        float n = tanhfast(acc[i][2][e] + b2 + r * (acc[i][3][e] + b3));
        size_t off = (size_t)(row0 + e) * 256 + outCol;
        float sv = sF[off];
        float o = (1.f - z) * n + z * sv;
        if (writeF32) outF[off] = o;
        else          outBf[off] = f2bf(o);
      }
    }
  }
}

extern "C" void kernel_launch(void* const* d_in, const int* in_sizes, int n_in,
                              void* d_out, int out_size, void* d_ws, size_t ws_size,
                              hipStream_t stream) {
  const float* x    = (const float*)d_in[0];
  const int*   par  = (const int*)d_in[1];
  const int*   chd  = (const int*)d_in[2];
  const int*   cnt  = (const int*)d_in[3];
  const float* Wres = (const float*)d_in[4];
  const float* bres = (const float*)d_in[5];
  const float* Wpar = (const float*)d_in[6];
  const float* bpar = (const float*)d_in[7];
  const float* Wnbr = (const float*)d_in[8];
  const float* bnbr = (const float*)d_in[9];
  const float* Wih  = (const float*)d_in[10];
  const float* Whh  = (const float*)d_in[11];
  const float* bih  = (const float*)d_in[12];
  const float* bhh  = (const float*)d_in[13];

  char* ws = (char*)d_ws;
  size_t off = 0;
  auto alloc = [&](size_t sz) { char* p = ws + off; off += (sz + 255) & ~(size_t)255; return p; };
  us*    Wg   = (us*)alloc((size_t)1024 * 512 * 2);
  us*    Wcat = (us*)alloc((size_t)256 * 512 * 2);
  us*    Wr   = (us*)alloc((size_t)256 * 256 * 2);
  float* bcat = (float*)alloc(256 * 4);
  float* bg   = (float*)alloc(1024 * 4);
  us*    xbf  = (us*)alloc((size_t)MM * 256 * 2);  // reused as s_bf after resize
  us*    h0   = (us*)alloc((size_t)MM * 256 * 2);
  us*    h1   = (us*)alloc((size_t)MM * 256 * 2);
  us*    Acat = (us*)alloc((size_t)MM * 512 * 2);
  us*    sbf  = xbf;
  float* sF   = (float*)d_out;  // s_f32 scratch lives in d_out (overwritten at end)

  k_prep<<<256, 256, 0, stream>>>(Wres, Wpar, bpar, Wnbr, bnbr, Wih, Whh, bih, bhh,
                                  Wr, Wcat, bcat, Wg, bg);
  k_f2bf<<<(MM * 256 / 8) / 256, 256, 0, stream>>>(x, xbf, MM * 256 / 8);

  // h0 = x @ W_resize^T + b_resize   (M/64 = 1024 blocks, single n-tile)
  k_gemm<0, 256, 256, 1><<<1024, 256, 0, stream>>>(
      xbf, xbf, 256, Wr, bres, h0, nullptr, nullptr, 0);

  us* hc = h0;
  for (int it = 0; it < 3; ++it) {
    us* hn = (hc == h0) ? h1 : h0;
    k_gather<<<MM / 4, 256, 0, stream>>>(hc, par, chd, cnt, Acat);
    // s = [p|m] @ Wcat^T + bcat  -> s_bf + s_f32(in d_out)
    k_gemm<1, 512, 512, 1><<<1024, 256, 0, stream>>>(
        Acat, Acat, 512, Wcat, bcat, sbf, sF, nullptr, 0);
    // fused GRU: [h|s] @ Wg^T, gate epilogue -> h_next (bf16) or d_out (f32, last)
    k_gemm<2, 512, 256, 4><<<4096, 256, 0, stream>>>(
        hc, sbf, 256, Wg, bg, hn, (float*)d_out, sF, (it == 2) ? 1 : 0);
    hc = hn;
  }
}

// Round 10
// 509.904 us; speedup vs baseline: 1.2390x; 1.2390x over previous
//
#include <hip/hip_runtime.h>

typedef unsigned short us;
typedef us us4 __attribute__((ext_vector_type(4)));
typedef us us8 __attribute__((ext_vector_type(8)));
typedef short bf16x8 __attribute__((ext_vector_type(8)));
typedef float f32x4 __attribute__((ext_vector_type(4)));

#define DEVI static __device__ __forceinline__

// constants for this problem instance
#define BB 16
#define NN 4096
#define PP 256
#define CC 8
#define MM (BB * NN)   // 65536

DEVI float bf2f(us u) { unsigned x = ((unsigned)u) << 16; return __builtin_bit_cast(float, x); }
DEVI us f2bf(float f) {
  unsigned x = __builtin_bit_cast(unsigned, f);
  x += 0x7fffu + ((x >> 16) & 1u);   // round to nearest even
  return (us)(x >> 16);
}

DEVI void gload_lds16(const void* g, void* l) {
  __builtin_amdgcn_global_load_lds(
      (const __attribute__((address_space(1))) void*)g,
      (__attribute__((address_space(3))) void*)l, 16, 0, 0);
}

DEVI float sigf(float x) { return 1.f / (1.f + __expf(-x)); }
DEVI float tanhfast(float a) {
  float aa = fabsf(a);
  float t = 1.f - 2.f / (1.f + __expf(2.f * aa));
  return copysignf(t, a);
}

// ---------------- weight prep: fp32 -> bf16, concatenated / gate-interleaved ----
// Wg layout (shuffle-free): row R -> J16 = R>>6, gate g = (R>>4)&3, c = R&15,
// output col j = J16*16 + c. Over K=512 ([h | s]):
//   g=0 (r):  [W_ih_r | W_hh_r]   g=1 (z): [W_ih_z | W_hh_z]
//   g=2 (xn): [W_ih_n | 0]        g=3 (hn): [0 | W_hh_n]
__global__ void k_prep(const float* __restrict__ Wres,
                       const float* __restrict__ Wpar, const float* __restrict__ bpar,
                       const float* __restrict__ Wnbr, const float* __restrict__ bnbr,
                       const float* __restrict__ Wih, const float* __restrict__ Whh,
                       const float* __restrict__ bih, const float* __restrict__ bhh,
                       us* __restrict__ Wr, us* __restrict__ Wcat, float* __restrict__ bcat,
                       us* __restrict__ Wg, float* __restrict__ bg) {
  int tid = blockIdx.x * blockDim.x + threadIdx.x;
  int nth = gridDim.x * blockDim.x;
  for (int i = tid; i < 256 * 256; i += nth) Wr[i] = f2bf(Wres[i]);
  for (int i = tid; i < 256 * 512; i += nth) {
    int o = i >> 9, k = i & 511;
    float v = (k < 256) ? Wpar[o * 256 + k] : Wnbr[o * 256 + (k - 256)];
    Wcat[i] = f2bf(v);
  }
  for (int i = tid; i < 256; i += nth) bcat[i] = bpar[i] + bnbr[i];
  for (int i = tid; i < 1024 * 512; i += nth) {
    int R = i >> 9, k = i & 511;
    int g = (R >> 4) & 3, j = ((R >> 6) << 4) + (R & 15);
    float v = 0.f;
    if (g == 0)      v = (k < 256) ? Wih[j * 256 + k]         : Whh[j * 256 + (k - 256)];
    else if (g == 1) v = (k < 256) ? Wih[(256 + j) * 256 + k] : Whh[(256 + j) * 256 + (k - 256)];
    else if (g == 2) v = (k < 256) ? Wih[(512 + j) * 256 + k] : 0.f;
    else             v = (k < 256) ? 0.f                      : Whh[(512 + j) * 256 + (k - 256)];
    Wg[i] = f2bf(v);
  }
  for (int i = tid; i < 1024; i += nth) {
    int g = (i >> 4) & 3, j = ((i >> 6) << 4) + (i & 15);
    float v;
    if (g == 0)      v = bih[j] + bhh[j];
    else if (g == 1) v = bih[256 + j] + bhh[256 + j];
    else if (g == 2) v = bih[512 + j];
    else             v = bhh[512 + j];
    bg[i] = v;
  }
}

// ---------------- x fp32 -> bf16 (vectorized) ----------------
__global__ __launch_bounds__(256) void k_f2bf(const float* __restrict__ x,
                                              us* __restrict__ o, int n8) {
  int i = blockIdx.x * blockDim.x + threadIdx.x;
  if (i >= n8) return;
  const float4* p = (const float4*)x + (size_t)i * 2;
  float4 a = p[0], b = p[1];
  us8 r;
  r[0] = f2bf(a.x); r[1] = f2bf(a.y); r[2] = f2bf(a.z); r[3] = f2bf(a.w);
  r[4] = f2bf(b.x); r[5] = f2bf(b.y); r[6] = f2bf(b.z); r[7] = f2bf(b.w);
  *(us8*)(o + (size_t)i * 8) = r;
}

// ---------------- children-avg: nbr[m] = avg(h[children(m)]) (bf16) ------------
// Parent gather is FUSED into EPI1's gload_lds staging (per-lane source addr),
// so this kernel only produces the neighbor average (half of old Acat).
__global__ __launch_bounds__(256)
void k_child(const us* __restrict__ h, const int* __restrict__ chd,
             const int* __restrict__ cnt, us* __restrict__ nbr) {
  int wid = (blockIdx.x * blockDim.x + threadIdx.x) >> 6;  // one wave per node
  int l = threadIdx.x & 63;
  int m = wid;                       // 0..MM-1
  int b = m >> 12;                   // N = 4096
  int c = cnt[m];
  float inv = 1.f / (float)c;
  const int* ch = chd + (size_t)m * CC;
  us4 cv[CC];
#pragma unroll
  for (int i = 0; i < CC; ++i) {
    int rowC = (b << 12) + ch[i];
    cv[i] = *((const us4*)(h + ((size_t)rowC << 8)) + l);
  }
  float a0 = 0.f, a1 = 0.f, a2 = 0.f, a3 = 0.f;
#pragma unroll
  for (int i = 0; i < CC; ++i) {
    float wgt = (i < c) ? 1.f : 0.f;
    a0 += wgt * bf2f(cv[i][0]); a1 += wgt * bf2f(cv[i][1]);
    a2 += wgt * bf2f(cv[i][2]); a3 += wgt * bf2f(cv[i][3]);
  }
  us4 nb;
  nb[0] = f2bf(a0 * inv); nb[1] = f2bf(a1 * inv);
  nb[2] = f2bf(a2 * inv); nb[3] = f2bf(a3 * inv);
  *((us4*)(nbr + ((size_t)m << 8)) + l) = nb;
}

// ---------------- MFMA K-step (256x256 tile) with compile-time j-mask ----------
// 8 waves as 2(M) x 4(N); per wave 128x64 output = acc[8][4].
template <int JM>
DEVI void mma8(const us* As, const us* Bs, int wr, int wc, int l,
               f32x4 (&acc)[8][4]) {
#pragma unroll
  for (int ks = 0; ks < 2; ++ks) {
    bf16x8 af[8], bfr[4];
#pragma unroll
    for (int i = 0; i < 8; ++i) {
      int row = wr * 128 + i * 16 + (l & 15);
      int kb = ((ks * 32 + (l >> 4) * 8) * 2) ^ ((row & 7) << 4);  // swizzled read
      af[i] = *(const bf16x8*)((const char*)As + row * 128 + kb);
    }
#pragma unroll
    for (int j = 0; j < 4; ++j)
      if (JM & (1 << j)) {
        int row = wc * 64 + j * 16 + (l & 15);
        int kb = ((ks * 32 + (l >> 4) * 8) * 2) ^ ((row & 7) << 4);
        bfr[j] = *(const bf16x8*)((const char*)Bs + row * 128 + kb);
      }
#pragma unroll
    for (int i = 0; i < 8; ++i)
#pragma unroll
      for (int j = 0; j < 4; ++j)
        if (JM & (1 << j))
          acc[i][j] = __builtin_amdgcn_mfma_f32_16x16x32_bf16(af[i], bfr[j], acc[i][j], 0, 0, 0);
  }
}

DEVI void raw_barrier() {
  __builtin_amdgcn_sched_barrier(0);
  __builtin_amdgcn_s_barrier();      // RAW barrier: no implicit vmcnt(0) drain
  __builtin_amdgcn_sched_barrier(0);
}

// ---------------- GEMM: C = A @ Bw^T (+bias), 256x256 tile, dbuf prefetch ------
// R6 core (best measured: EPI2 103 µs): compile-time KTOT/KSPLIT/NT, XCD-chunked
// flat grid, K-loop {stage(t+1) -> s_waitcnt vmcnt(8) counted -> raw barrier ->
// MFMA -> raw barrier}. Raw s_barrier (not __syncthreads) keeps prefetched
// loads in flight across barriers (measured R5->R6).
// GA: A0 rows are gathered through par[] (h[parent[row]]) — gload_lds's global
// source is per-lane, so indirection is free; 8 lanes/row -> 128B segments.
// NOTE: never request >2 waves/SIMD — acc alone is 128 regs; at 4/SIMD
// (128-reg budget) the R2 experiment spilled: 2.4 GB/dispatch scratch, 3x slow.
template <int EPI, int KTOT, int KSPLIT, int NT, bool GA>
__global__ __launch_bounds__(512, 2)
void k_gemm(const us* __restrict__ A0, const us* __restrict__ A1, int strideA,
            const us* __restrict__ Bw, const float* __restrict__ bias,
            us* __restrict__ outBf, float* __restrict__ outF,
            const float* __restrict__ sF, int writeF32,
            const int* __restrict__ par) {
  __shared__ __align__(16) us As[2][256 * 64];
  __shared__ __align__(16) us Bs[2][256 * 64];
  int tid = threadIdx.x;
  int w = tid >> 6, l = tid & 63;
  int wr = w >> 2, wc = w & 3;
  int bid = blockIdx.x;
  int per = gridDim.x >> 3;
  int g = (bid & 7) * per + (bid >> 3);
  int mi, ni;
  if (NT == 1) { mi = g; ni = 0; }
  else         { mi = g / NT; ni = g - mi * NT; }
  int mBase = mi * 256, nBase = ni * 256;
  f32x4 acc[8][4] = {};

  // parent-gathered row index per staging row (GA only). Tile spans 256 rows
  // inside ONE batch (mBase % 4096 == 0 or 256-aligned within batch).
  int prow[4];
  if (GA) {
    int bb = (mBase >> 12) << 12;
#pragma unroll
    for (int c = 0; c < 4; ++c)
      prow[c] = bb + par[mBase + c * 64 + (tid >> 3)];
  }

  auto stage = [&](int t) {
    int kt = t * 64, buf = t & 1;
    const us* aSrc; int kOff;
    if (kt < KSPLIT) { aSrc = A0; kOff = kt; }
    else             { aSrc = A1; kOff = kt - KSPLIT; }
#pragma unroll
    for (int c = 0; c < 4; ++c) {
      int row = c * 64 + (tid >> 3);
      int kb = ((tid & 7) * 16) ^ ((row & 7) << 4);   // pre-swizzled global source
      const char* ga;
      if (GA && kt < KSPLIT)
        ga = (const char*)(aSrc + (size_t)prow[c] * strideA + kOff) + kb;
      else
        ga = (const char*)(aSrc + (size_t)(mBase + row) * strideA + kOff) + kb;
      gload_lds16(ga, (char*)As[buf] + row * 128 + (tid & 7) * 16);
      const char* gb = (const char*)(Bw + (size_t)(nBase + row) * KTOT + kt) + kb;
      gload_lds16(gb, (char*)Bs[buf] + row * 128 + (tid & 7) * 16);
    }
  };

  constexpr int NKT = KTOT / 64;
  stage(0);
#pragma unroll
  for (int t = 0; t < NKT; ++t) {
    if (t + 1 < NKT) {
      stage(t + 1);
      asm volatile("s_waitcnt vmcnt(8)" ::: "memory");  // tile t done; t+1 in flight
    } else {
      asm volatile("s_waitcnt vmcnt(0)" ::: "memory");
    }
    raw_barrier();                     // LDS tile-t writes visible to all waves
    int buf = t & 1;
    if (EPI == 2) {
      if (t * 64 < KSPLIT) mma8<0b0111>(As[buf], Bs[buf], wr, wc, l, acc);  // skip hn
      else                 mma8<0b1011>(As[buf], Bs[buf], wr, wc, l, acc);  // skip xn
    } else {
      mma8<0b1111>(As[buf], Bs[buf], wr, wc, l, acc);
    }
    raw_barrier();                     // all reads of buf done before restage
  }

  int rBase0 = mBase + wr * 128;
  int cBase0 = nBase + wc * 64;
  if (EPI == 0 || EPI == 1) {
#pragma unroll
    for (int i = 0; i < 8; ++i)
#pragma unroll
      for (int j = 0; j < 4; ++j) {
        int col = cBase0 + j * 16 + (l & 15);
        int row0 = rBase0 + i * 16 + ((l >> 4) << 2);
        float bb = bias[col];
#pragma unroll
        for (int e = 0; e < 4; ++e) {
          float v = acc[i][j][e] + bb;
          size_t off = (size_t)(row0 + e) * 256 + col;
          outBf[off] = f2bf(v);
          if (EPI == 1) outF[off] = v;
        }
      }
  } else {
    // shuffle-free: j-fragment == gate (wave spans 64 gate-cols = 16 out cols)
    int outCol = ((nBase >> 6) + wc) * 16 + (l & 15);
    float b0 = bias[cBase0 + 0  + (l & 15)];
    float b1 = bias[cBase0 + 16 + (l & 15)];
    float b2 = bias[cBase0 + 32 + (l & 15)];
    float b3 = bias[cBase0 + 48 + (l & 15)];
#pragma unroll
    for (int i = 0; i < 8; ++i) {
      int row0 = rBase0 + i * 16 + ((l >> 4) << 2);
#pragma unroll
      for (int e = 0; e < 4; ++e) {
        float r = sigf(acc[i][0][e] + b0);
        float z = sigf(acc[i][1][e] + b1);
        float n = tanhfast(acc[i][2][e] + b2 + r * (acc[i][3][e] + b3));
        size_t off = (size_t)(row0 + e) * 256 + outCol;
        float sv = sF[off];
        float o = (1.f - z) * n + z * sv;
        if (writeF32) outF[off] = o;
        else          outBf[off] = f2bf(o);
      }
    }
  }
}

extern "C" void kernel_launch(void* const* d_in, const int* in_sizes, int n_in,
                              void* d_out, int out_size, void* d_ws, size_t ws_size,
                              hipStream_t stream) {
  const float* x    = (const float*)d_in[0];
  const int*   par  = (const int*)d_in[1];
  const int*   chd  = (const int*)d_in[2];
  const int*   cnt  = (const int*)d_in[3];
  const float* Wres = (const float*)d_in[4];
  const float* bres = (const float*)d_in[5];
  const float* Wpar = (const float*)d_in[6];
  const float* bpar = (const float*)d_in[7];
  const float* Wnbr = (const float*)d_in[8];
  const float* bnbr = (const float*)d_in[9];
  const float* Wih  = (const float*)d_in[10];
  const float* Whh  = (const float*)d_in[11];
  const float* bih  = (const float*)d_in[12];
  const float* bhh  = (const float*)d_in[13];

  char* ws = (char*)d_ws;
  size_t off = 0;
  auto alloc = [&](size_t sz) { char* p = ws + off; off += (sz + 255) & ~(size_t)255; return p; };
  us*    Wg   = (us*)alloc((size_t)1024 * 512 * 2);
  us*    Wcat = (us*)alloc((size_t)256 * 512 * 2);
  us*    Wr   = (us*)alloc((size_t)256 * 256 * 2);
  float* bcat = (float*)alloc(256 * 4);
  float* bg   = (float*)alloc(1024 * 4);
  us*    xbf  = (us*)alloc((size_t)MM * 256 * 2);  // reused as s_bf after resize
  us*    h0   = (us*)alloc((size_t)MM * 256 * 2);
  us*    h1   = (us*)alloc((size_t)MM * 256 * 2);
  us*    nbr  = (us*)alloc((size_t)MM * 256 * 2);
  us*    sbf  = xbf;
  float* sF   = (float*)d_out;  // s_f32 scratch lives in d_out (overwritten at end)

  k_prep<<<256, 256, 0, stream>>>(Wres, Wpar, bpar, Wnbr, bnbr, Wih, Whh, bih, bhh,
                                  Wr, Wcat, bcat, Wg, bg);
  k_f2bf<<<(MM * 256 / 8) / 256, 256, 0, stream>>>(x, xbf, MM * 256 / 8);

  // h0 = x @ W_resize^T + b_resize   (M/256 = 256 blocks, single n-tile)
  k_gemm<0, 256, 256, 1, false><<<256, 512, 0, stream>>>(
      xbf, xbf, 256, Wr, bres, h0, nullptr, nullptr, 0, nullptr);

  us* hc = h0;
  for (int it = 0; it < 3; ++it) {
    us* hn = (hc == h0) ? h1 : h0;
    k_child<<<MM / 4, 256, 0, stream>>>(hc, chd, cnt, nbr);
    // s = [h[par] | nbr] @ Wcat^T + bcat  (parent gather fused into staging)
    k_gemm<1, 512, 256, 1, true><<<256, 512, 0, stream>>>(
        hc, nbr, 256, Wcat, bcat, sbf, sF, nullptr, 0, par);
    // fused GRU: [h|s] @ Wg^T, gate epilogue -> h_next (bf16) or d_out (f32, last)
    k_gemm<2, 512, 256, 4, false><<<1024, 512, 0, stream>>>(
        hc, sbf, 256, Wg, bg, hn, (float*)d_out, sF, (it == 2) ? 1 : 0, nullptr);
    hc = hn;
  }
}